// Round 1
// baseline (593.842 us; speedup 1.0000x reference)
//
#include <hip/hip_runtime.h>
#include <hip/hip_bf16.h>
#include <stdint.h>

#define B_ 4096
#define D_ 2048
#define U_ 2048
#define K_ 4096   // D + U
#define N_ 8192   // 4 * U

typedef __bf16 bf16x8 __attribute__((ext_vector_type(8)));
typedef float floatx4 __attribute__((ext_vector_type(4)));

__device__ __forceinline__ unsigned short f2bf(float f) {
    union { float f; unsigned int u; } v; v.f = f;
    unsigned int u = v.u;
    unsigned int r = (u + 0x7fffu + ((u >> 16) & 1u)) >> 16;  // round-nearest-even
    return (unsigned short)r;
}

__device__ __forceinline__ float bf2f(unsigned short b) {
    union { unsigned int u; float f; } v;
    v.u = ((unsigned int)b) << 16;
    return v.f;
}

// ---------------------------------------------------------------------------
// Kernel 1: pack [x | h] -> Abf[4096][4096] bf16 (row-major, K contiguous)
// ---------------------------------------------------------------------------
__global__ void k_convA(const float* __restrict__ x, const float* __restrict__ h,
                        unsigned short* __restrict__ Abf) {
    int t = blockIdx.x * blockDim.x + threadIdx.x;   // one float4 each
    long e = (long)t * 4;
    int b = (int)(e >> 12);       // / 4096
    int k = (int)(e & 4095);
    const float* src = (k < D_) ? (x + (size_t)b * D_ + k)
                                : (h + (size_t)b * U_ + (k - D_));
    float4 v = *(const float4*)src;
    ushort4 o;
    o.x = f2bf(v.x); o.y = f2bf(v.y); o.z = f2bf(v.z); o.w = f2bf(v.w);
    *(ushort4*)(Abf + e) = o;
}

// ---------------------------------------------------------------------------
// Kernel 2: transpose weights -> Bt[8192][4096] bf16 (N-major, K contiguous)
// Bt[g*2048 + u][k] = (k < 2048) ? Wx_g[k][u] : Wh_g[k-2048][u]
// ---------------------------------------------------------------------------
__global__ void k_convB(const float* __restrict__ Wx0, const float* __restrict__ Wx1,
                        const float* __restrict__ Wx2, const float* __restrict__ Wx3,
                        const float* __restrict__ Wh0, const float* __restrict__ Wh1,
                        const float* __restrict__ Wh2, const float* __restrict__ Wh3,
                        unsigned short* __restrict__ Bt) {
    __shared__ float tile[32][33];   // +1 pad: conflict-free transposed reads
    int g  = blockIdx.z;
    int k0 = blockIdx.x * 32;
    int u0 = blockIdx.y * 32;
    const float* W;
    if (k0 < D_) {
        W = (g == 0 ? Wx0 : g == 1 ? Wx1 : g == 2 ? Wx2 : Wx3) + (size_t)k0 * U_;
    } else {
        W = (g == 0 ? Wh0 : g == 1 ? Wh1 : g == 2 ? Wh2 : Wh3) + (size_t)(k0 - D_) * U_;
    }
    int tx = threadIdx.x & 31, ty = threadIdx.x >> 5;   // 32 x 8
    #pragma unroll
    for (int j = 0; j < 4; ++j)
        tile[ty + 8 * j][tx] = W[(size_t)(ty + 8 * j) * U_ + u0 + tx];
    __syncthreads();
    #pragma unroll
    for (int j = 0; j < 4; ++j) {
        int u = u0 + ty + 8 * j;
        Bt[(size_t)(g * U_ + u) * K_ + k0 + tx] = f2bf(tile[tx][ty + 8 * j]);
    }
}

// ---------------------------------------------------------------------------
// Kernel 3: GEMM  Z[4096][8192](bf16) = Abf[4096][4096] * Bt[8192][4096]^T
// m97 structure: 128x128 tile, BK=32, global_load_lds(16B), 16x16x32 MFMA
// ---------------------------------------------------------------------------
__device__ __forceinline__ void gload16(const unsigned short* g, unsigned short* l) {
    __builtin_amdgcn_global_load_lds(
        (const __attribute__((address_space(1))) void*)g,
        (__attribute__((address_space(3))) void*)l, 16, 0, 0);
}

__global__ __launch_bounds__(256) void k_gemm(const unsigned short* __restrict__ A,
                                              const unsigned short* __restrict__ Bt,
                                              unsigned short* __restrict__ Z) {
    __shared__ __align__(16) unsigned short As[128 * 32];
    __shared__ __align__(16) unsigned short Bs[128 * 32];
    const int m0  = blockIdx.y * 128;
    const int n0  = blockIdx.x * 128;
    const int tid = threadIdx.x;
    const int w   = tid >> 6;      // wave 0..3
    const int l   = tid & 63;      // lane

    // staging: wave w covers tile rows [w*16, w*16+16) (q=0) and +64 (q=1)
    const unsigned short* gA = A  + (size_t)(m0 + w * 16 + (l >> 2)) * K_ + (l & 3) * 8;
    const unsigned short* gB = Bt + (size_t)(n0 + w * 16 + (l >> 2)) * K_ + (l & 3) * 8;
    unsigned short* lA = As + w * 512;   // wave-uniform LDS base
    unsigned short* lB = Bs + w * 512;

    const int r     = l & 15;
    const int quad  = l >> 4;
    const int m_off = (w & 1) * 64;
    const int n_off = (w >> 1) * 64;

    floatx4 acc[4][4];
    #pragma unroll
    for (int i = 0; i < 4; ++i)
        #pragma unroll
        for (int j = 0; j < 4; ++j)
            #pragma unroll
            for (int e = 0; e < 4; ++e) acc[i][j][e] = 0.f;

    for (int k0 = 0; k0 < K_; k0 += 32) {
        __syncthreads();
        gload16(gA + k0,                  lA);
        gload16(gA + k0 + (size_t)64 * K_, lA + 2048);
        gload16(gB + k0,                  lB);
        gload16(gB + k0 + (size_t)64 * K_, lB + 2048);
        __syncthreads();

        bf16x8 af[4], bfv[4];
        #pragma unroll
        for (int i = 0; i < 4; ++i)
            af[i] = *(const bf16x8*)(As + ((m_off + i * 16 + r) * 32 + quad * 8));
        #pragma unroll
        for (int j = 0; j < 4; ++j)
            bfv[j] = *(const bf16x8*)(Bs + ((n_off + j * 16 + r) * 32 + quad * 8));
        #pragma unroll
        for (int i = 0; i < 4; ++i)
            #pragma unroll
            for (int j = 0; j < 4; ++j)
                acc[i][j] = __builtin_amdgcn_mfma_f32_16x16x32_bf16(
                    af[i], bfv[j], acc[i][j], 0, 0, 0);
    }

    // epilogue: C/D layout col = lane&15, row = quad*4 + reg  [m89/m91 verified]
    #pragma unroll
    for (int i = 0; i < 4; ++i) {
        #pragma unroll
        for (int j = 0; j < 4; ++j) {
            int col = n0 + n_off + j * 16 + r;
            #pragma unroll
            for (int e = 0; e < 4; ++e) {
                int row = m0 + m_off + i * 16 + quad * 4 + e;
                Z[(size_t)row * N_ + col] = f2bf(acc[i][j][e]);
            }
        }
    }
}

// ---------------------------------------------------------------------------
// Kernel 4: gate fusion. Reads Z(bf16), c, biases; writes h_new, c_new (fp32)
// ---------------------------------------------------------------------------
__device__ __forceinline__ float sigmoidf_(float x) { return 1.0f / (1.0f + expf(-x)); }

__global__ void k_gates(const unsigned short* __restrict__ Z, const float* __restrict__ c,
                        const float* __restrict__ bfp, const float* __restrict__ bip,
                        const float* __restrict__ bop, const float* __restrict__ bgp,
                        float* __restrict__ hout, float* __restrict__ cout) {
    int t = blockIdx.x * blockDim.x + threadIdx.x;   // 4 u-values each
    long e = (long)t * 4;
    int b = (int)(e >> 11);      // / 2048
    int u = (int)(e & 2047);
    const size_t zr = (size_t)b * N_;
    ushort4 zf4 = *(const ushort4*)(Z + zr + u);
    ushort4 zi4 = *(const ushort4*)(Z + zr + U_ + u);
    ushort4 zo4 = *(const ushort4*)(Z + zr + 2 * U_ + u);
    ushort4 zg4 = *(const ushort4*)(Z + zr + 3 * U_ + u);
    float4 bfv = *(const float4*)(bfp + u);
    float4 biv = *(const float4*)(bip + u);
    float4 bov = *(const float4*)(bop + u);
    float4 bgv = *(const float4*)(bgp + u);
    float4 cv  = *(const float4*)(c + e);

    float zf[4] = {bf2f(zf4.x), bf2f(zf4.y), bf2f(zf4.z), bf2f(zf4.w)};
    float zi[4] = {bf2f(zi4.x), bf2f(zi4.y), bf2f(zi4.z), bf2f(zi4.w)};
    float zo[4] = {bf2f(zo4.x), bf2f(zo4.y), bf2f(zo4.z), bf2f(zo4.w)};
    float zg[4] = {bf2f(zg4.x), bf2f(zg4.y), bf2f(zg4.z), bf2f(zg4.w)};
    float bff[4] = {bfv.x, bfv.y, bfv.z, bfv.w};
    float bif[4] = {biv.x, biv.y, biv.z, biv.w};
    float bof[4] = {bov.x, bov.y, bov.z, bov.w};
    float bgf[4] = {bgv.x, bgv.y, bgv.z, bgv.w};
    float cf[4]  = {cv.x, cv.y, cv.z, cv.w};

    float4 ho, co;
    float hh[4], cc[4];
    #pragma unroll
    for (int q = 0; q < 4; ++q) {
        float f = sigmoidf_(zf[q] + bff[q]);
        float i = sigmoidf_(zi[q] + bif[q]);
        float o = sigmoidf_(zo[q] + bof[q]);
        float g = tanhf(zg[q] + bgf[q]);
        float cn = f * cf[q] + i * g;
        cc[q] = cn;
        hh[q] = o * tanhf(cn);
    }
    ho.x = hh[0]; ho.y = hh[1]; ho.z = hh[2]; ho.w = hh[3];
    co.x = cc[0]; co.y = cc[1]; co.z = cc[2]; co.w = cc[3];
    *(float4*)(hout + e) = ho;
    *(float4*)(cout + e) = co;
}

// ---------------------------------------------------------------------------
extern "C" void kernel_launch(void* const* d_in, const int* in_sizes, int n_in,
                              void* d_out, int out_size, void* d_ws, size_t ws_size,
                              hipStream_t stream) {
    const float* x   = (const float*)d_in[0];
    const float* h   = (const float*)d_in[1];
    const float* c   = (const float*)d_in[2];
    const float* Wxf = (const float*)d_in[3];
    const float* Wxi = (const float*)d_in[4];
    const float* Wxo = (const float*)d_in[5];
    const float* Wxg = (const float*)d_in[6];
    const float* bf  = (const float*)d_in[7];
    const float* bi  = (const float*)d_in[8];
    const float* bo  = (const float*)d_in[9];
    const float* bg  = (const float*)d_in[10];
    const float* Whf = (const float*)d_in[11];
    const float* Whi = (const float*)d_in[12];
    const float* Who = (const float*)d_in[13];
    const float* Whg = (const float*)d_in[14];
    float* out = (float*)d_out;

    // workspace layout: Abf (33.5 MB) | Bt (67 MB) | Z bf16 (67 MB)
    unsigned short* Abf = (unsigned short*)d_ws;
    unsigned short* Bt  = Abf + (size_t)B_ * K_;
    unsigned short* Z   = Bt + (size_t)N_ * K_;

    k_convA<<<(B_ * K_ / 4) / 256, 256, 0, stream>>>(x, h, Abf);
    k_convB<<<dim3(K_ / 32, U_ / 32, 4), 256, 0, stream>>>(
        Wxf, Wxi, Wxo, Wxg, Whf, Whi, Who, Whg, Bt);
    k_gemm<<<dim3(N_ / 128, B_ / 128), 256, 0, stream>>>(Abf, Bt, Z);
    k_gates<<<(B_ * U_ / 4) / 256, 256, 0, stream>>>(
        Z, c, bf, bi, bo, bg, out, out + (size_t)B_ * U_);
}